// Round 15
// baseline (91.047 us; speedup 1.0000x reference)
//
#include <hip/hip_runtime.h>
#include <math.h>

#define HW     262144   // 512*512
#define WIDTH  512
#define BB     4
#define NN     32
#define KK     256
#define PP     8192
#define EPSF   1e-4f
#define ONE_M_EPS (1.0f - 1e-4f)

// ---- workspace layout (floats) ----
#define WS_BITS  0         // 4MB bitplanes: uchar4[(b*4+g)*65536 + v]  = 1048576 floats
#define WS_INST  1048576   // [1024 blocks][64]  (il*2 + {sum,cnt})    = 65536
#define WS_FOCAL 1114112   // [2][256][2] = 1024
#define WS_WH    1115136   // [256][2]    = 512
#define WS_TAN   1115648   // [32]
#define WS_VAR   1115680   // [128]
// end = 1115808 floats = 4.46 MB (R11 proved ws_size >= 16.8 MB)

// ---- mega1 block partition: compress first, small families fill ----
#define NBLK_CMP   512   // (b:4) x (grp:4 of 8 planes) x (seg:32 of 32KB)
#define NBLK_WH    256
#define NBLK_FOCAL 512   // 2 tensors x 256
#define NBLK_TAN   32
#define NBLK_VAR   128
#define OFF_WH     NBLK_CMP
#define OFF_FOCAL  (OFF_WH + NBLK_WH)
#define OFF_TAN    (OFF_FOCAL + NBLK_FOCAL)
#define OFF_VAR    (OFF_TAN + NBLK_TAN)
#define NBLK_M1    (OFF_VAR + NBLK_VAR)   // 1440

#define NBLK_M2    1024  // (b:4) x (chunk:256): 256 f4 px, all 32 instances

__device__ __forceinline__ float ftanh(float x) {
    float e = __expf(2.0f * x);
    return 1.0f - 2.0f / (e + 1.0f);
}

__device__ __forceinline__ float wave_reduce(float v) {
    #pragma unroll
    for (int off = 1; off < 64; off <<= 1) v += __shfl_xor(v, off, 64);
    return v;
}

__device__ __forceinline__ float block_reduce(float v, float* sbuf) {
    v = wave_reduce(v);
    int lane = threadIdx.x & 63, wid = threadIdx.x >> 6;
    __syncthreads();
    if (lane == 0) sbuf[wid] = v;
    __syncthreads();
    float r = 0.f;
    if (threadIdx.x == 0) {
        for (int i = 0; i < 4; ++i) r += sbuf[i];
    }
    return r;
}

// ---- bitplane compress: R10's proven sequential sweep, zero compute ----
// idx: b = idx>>7, grp = (idx>>5)&3 (8 planes), seg = idx&31 (32KB segment).
// Per it (8, unrolled): 8 sequential plane reads (32 VGPR batch) -> 1 byte/px.
__device__ __forceinline__ void cmp_part(int idx, const float* __restrict__ masks,
                                         float* __restrict__ ws) {
    const int tid = threadIdx.x;
    const int b = idx >> 7, grp = (idx >> 5) & 3, seg = idx & 31;
    const float4* mbase = (const float4*)masks + ((size_t)(b * NN + grp * 8) << 16);
    const int segf4 = seg * 2048;     // 2048 f4 = 32KB
    uchar4* bits = (uchar4*)ws + (((size_t)(b * 4 + grp)) << 16);
    #pragma unroll
    for (int it = 0; it < 8; ++it) {
        int v = segf4 + it * 256 + tid;
        float4 mk[8];
        #pragma unroll
        for (int i = 0; i < 8; ++i) mk[i] = mbase[((size_t)i << 16) + v];
        unsigned bb0 = 0, bb1 = 0, bb2 = 0, bb3 = 0;
        #pragma unroll
        for (int i = 0; i < 8; ++i) {
            bb0 |= (mk[i].x != 0.f ? 1u : 0u) << i;
            bb1 |= (mk[i].y != 0.f ? 1u : 0u) << i;
            bb2 |= (mk[i].z != 0.f ? 1u : 0u) << i;
            bb3 |= (mk[i].w != 0.f ? 1u : 0u) << i;
        }
        bits[v] = make_uchar4((unsigned char)bb0, (unsigned char)bb1,
                              (unsigned char)bb2, (unsigned char)bb3);
    }
}

// ---- lean sweep: se/sg once per pixel, il-loop has ZERO loads (bit tests) ----
// idx: b = idx>>8, chunk = idx&255. Thread owns one f4 (4 px), v = chunk*256+tid.
__device__ __forceinline__ void sweep_part(int idx, const float* __restrict__ ae,
                                           const int* __restrict__ centers,
                                           float* __restrict__ ws,
                                           float* __restrict__ smem) {
    const int tid = threadIdx.x, lane = tid & 63, w = tid >> 6;
    const int b = idx >> 8, chunk = idx & 255;
    const int v = chunk * 256 + tid;          // f4 index 0..65535
    float* s_cy = smem;            // [32]
    float* s_cx = smem + 32;       // [32]
    float* s_part = smem + 64;     // [4][64]
    if (tid < NN) {
        int cb = (b * NN + tid) * 2;
        s_cy[tid] = centers[cb]     * (1.0f / 512.0f);
        s_cx[tid] = centers[cb + 1] * (1.0f / 512.0f);
    }
    __syncthreads();

    const float4* aeb = (const float4*)ae + (size_t)b * 4 * 65536;
    float4 a0 = aeb[v];
    float4 a1 = aeb[65536 + v];
    float4 a2 = aeb[131072 + v];
    float4 a3 = aeb[196608 + v];
    const uchar4* bits = (const uchar4*)ws;
    uchar4 q0 = bits[(((size_t)(b * 4 + 0)) << 16) + v];
    uchar4 q1 = bits[(((size_t)(b * 4 + 1)) << 16) + v];
    uchar4 q2 = bits[(((size_t)(b * 4 + 2)) << 16) + v];
    uchar4 q3 = bits[(((size_t)(b * 4 + 3)) << 16) + v];
    unsigned wj[4];
    wj[0] = (unsigned)q0.x | ((unsigned)q1.x << 8) | ((unsigned)q2.x << 16) | ((unsigned)q3.x << 24);
    wj[1] = (unsigned)q0.y | ((unsigned)q1.y << 8) | ((unsigned)q2.y << 16) | ((unsigned)q3.y << 24);
    wj[2] = (unsigned)q0.z | ((unsigned)q1.z << 8) | ((unsigned)q2.z << 16) | ((unsigned)q3.z << 24);
    wj[3] = (unsigned)q0.w | ((unsigned)q1.w << 8) | ((unsigned)q2.w << 16) | ((unsigned)q3.w << 24);

    int pix0 = v * 4;
    float fy  = (float)(pix0 >> 9)  * (1.0f / 512.0f);
    float fx0 = (float)(pix0 & 511) * (1.0f / 512.0f);
    float se0[4], se1[4], sg0[4], sg1[4];
    #pragma unroll
    for (int j = 0; j < 4; ++j) {
        se0[j] = ftanh((&a0.x)[j]) + fy;
        se1[j] = ftanh((&a1.x)[j]) + fx0 + (float)j * (1.0f / 512.0f);
        sg0[j] = __expf((&a2.x)[j]);
        sg1[j] = __expf((&a3.x)[j]);
    }
    #pragma unroll 4
    for (int il = 0; il < NN; ++il) {
        float ccy = s_cy[il], ccx = s_cx[il];
        float sum = 0.f, cnt = 0.f;
        #pragma unroll
        for (int j = 0; j < 4; ++j) {
            bool mb = (wj[j] >> il) & 1u;          // mask bit (0/1)
            float dy = se0[j] - ccy, dx = se1[j] - ccx;
            float s  = fmaf(dx * dx, sg1[j], dy * dy * sg0[j]);
            float e  = __expf(-s);
            float pc = fminf(fmaxf(e, EPSF), ONE_M_EPS);
            float omp = 1.0f - pc;
            // pos: log(pc)*omp^2 ; neg: log(omp)*pc^2 (neg_w==1, binary mask)
            float A = mb ? pc : omp;
            float B = 1.0f - A;
            sum = fmaf(__logf(A), B * B, sum);
            cnt += mb ? 1.0f : 0.0f;
        }
        float r0 = wave_reduce(sum);
        float r1 = wave_reduce(cnt);
        if (lane == 0) {
            s_part[w * 64 + il * 2 + 0] = r0;
            s_part[w * 64 + il * 2 + 1] = r1;
        }
    }
    __syncthreads();
    if (tid < 64) {
        float s = s_part[tid] + s_part[64 + tid] + s_part[128 + tid] + s_part[192 + tid];
        ws[WS_INST + (size_t)idx * 64 + tid] = s;
    }
}

// ---- cls/kp focal: idx = t*256 + blk, 4 iters ----
__device__ __forceinline__ void focal_part(int idx, const float* __restrict__ cls_out,
                                           const float* __restrict__ cls_mask,
                                           const float* __restrict__ kp_out,
                                           const float* __restrict__ kp_mask,
                                           float* __restrict__ ws, float* sbuf) {
    int t = idx >> 8, blk = idx & 255;
    const float4* po = (const float4*)(t == 0 ? cls_out : kp_out);
    const float4* pm = (const float4*)(t == 0 ? cls_mask : kp_mask);
    float sum = 0.f, cnt = 0.f;
    #pragma unroll
    for (int it = 0; it < 4; ++it) {
        int i = blk * 256 + threadIdx.x + it * 65536;
        float4 xo = po[i], xm = pm[i];
        #pragma unroll
        for (int j = 0; j < 4; ++j) {
            float x = (&xo.x)[j], gt = (&xm.x)[j];
            float p = 1.0f / (1.0f + __expf(-x));
            p = fminf(fmaxf(p, EPSF), ONE_M_EPS);
            float omp = 1.0f - p;
            float pos_t = __logf(p) * omp * omp;
            float og = 1.0f - gt;
            float negw = og * og; negw *= negw;
            float neg_t = __logf(omp) * p * p * negw;
            bool ispos = (gt == 1.0f);
            sum += ispos ? pos_t : neg_t;
            cnt += ispos ? 1.0f : 0.0f;
        }
    }
    float r0 = block_reduce(sum, sbuf);
    float r1 = block_reduce(cnt, sbuf);
    if (threadIdx.x == 0) {
        ws[WS_FOCAL + idx * 2 + 0] = r0;
        ws[WS_FOCAL + idx * 2 + 1] = r1;
    }
}

__device__ __forceinline__ void wh_part(int blk, const float* __restrict__ o,
                                        const float* __restrict__ tg,
                                        const float* __restrict__ m,
                                        float* __restrict__ ws, float* sbuf) {
    const float4* po  = (const float4*)o;
    const float4* pt  = (const float4*)tg;
    const float4* pmk = (const float4*)m;
    float sl = 0.f, ms = 0.f;
    #pragma unroll
    for (int it = 0; it < 8; ++it) {
        int i = blk * 256 + threadIdx.x + it * 65536;
        float4 a = po[i], b = pt[i], c = pmk[i];
        #pragma unroll
        for (int j = 0; j < 4; ++j) {
            float mm = (&c.x)[j];
            float d  = (&a.x)[j] * mm - (&b.x)[j] * mm;
            float ad = fabsf(d);
            sl += (ad < 1.0f) ? 0.5f * d * d : (ad - 0.5f);
            ms += mm;
        }
    }
    float r0 = block_reduce(sl, sbuf);
    float r1 = block_reduce(ms, sbuf);
    if (threadIdx.x == 0) {
        ws[WS_WH + blk * 2 + 0] = r0;
        ws[WS_WH + blk * 2 + 1] = r1;
    }
}

__device__ __forceinline__ void tan_part(int idx, const float* __restrict__ tan_out,
                                         const float* __restrict__ normals,
                                         const int* __restrict__ pts,
                                         float* __restrict__ ws, float* sbuf) {
    int b = idx >> 3, seg = idx & 7;
    float s = 0.f;
    for (int p = seg * 1024 + threadIdx.x; p < seg * 1024 + 1024; p += 256) {
        int base = (b * PP + p) * 2;
        int py = pts[base], px = pts[base + 1];
        int pix = py * WIDTH + px;
        float t0 = tan_out[b * 2 * HW + pix];
        float t1 = tan_out[b * 2 * HW + HW + pix];
        float inv = 1.0f / fmaxf(sqrtf(t0 * t0 + t1 * t1), EPSF);
        float n0 = normals[base], n1 = normals[base + 1];
        s += 1.0f - (n0 * t0 + n1 * t1) * inv;
    }
    float r = block_reduce(s, sbuf);
    if (threadIdx.x == 0) ws[WS_TAN + idx] = r;
}

__device__ __forceinline__ void var_part(int idx, const float* __restrict__ ae,
                                         const int* __restrict__ centers,
                                         const int* __restrict__ kps,
                                         float* __restrict__ ws, float* smem) {
    int n = idx & 31, b = idx >> 5;
    float* cy = smem, *cx = smem + 32, *sbuf = smem + 64;
    if (threadIdx.x < NN) {
        int cb = (b * NN + threadIdx.x) * 2;
        cy[threadIdx.x] = centers[cb]     * (1.0f / 512.0f);
        cx[threadIdx.x] = centers[cb + 1] * (1.0f / 512.0f);
    }
    __syncthreads();
    int k = threadIdx.x;
    int kb = ((b * NN + n) * KK + k) * 2;
    int ky = kps[kb], kx = kps[kb + 1];
    int pix = ky * WIDTH + kx;
    const float* aeb = ae + (size_t)b * 4 * HW;
    float se0 = ftanh(aeb[pix])      + ky * (1.0f / 512.0f);
    float se1 = ftanh(aeb[HW + pix]) + kx * (1.0f / 512.0f);
    float sg0 = __expf(aeb[2 * HW + pix]);
    float sg1 = __expf(aeb[3 * HW + pix]);
    float own = 0.f, mx = -1e30f;
    #pragma unroll
    for (int m = 0; m < NN; ++m) {
        float d0 = se0 - cy[m], d1 = se1 - cx[m];
        float dist = __expf(-(d0 * d0 * sg0 + d1 * d1 * sg1));
        mx = fmaxf(mx, dist);
        if (m == n) own = dist;
    }
    float r = block_reduce(fabsf(own - mx), sbuf);
    if (threadIdx.x == 0) ws[WS_VAR + b * NN + n] = r;
}

// ---- mega1: bitplane compress + all small families ----
__global__ void __launch_bounds__(256)
k_mega1(const float* __restrict__ cls_out, const float* __restrict__ wh_out,
        const float* __restrict__ kp_out,  const float* __restrict__ ae_out,
        const float* __restrict__ tan_out, const float* __restrict__ cls_mask,
        const float* __restrict__ wh_target, const float* __restrict__ wh_mask,
        const float* __restrict__ kp_mask, const float* __restrict__ ae_masks,
        const float* __restrict__ tan_normals,
        const int* __restrict__ centers, const int* __restrict__ kps,
        const int* __restrict__ tan_points, float* __restrict__ ws) {
    __shared__ float smem[256];
    int bid = blockIdx.x;
    if (bid < NBLK_CMP) {
        cmp_part(bid, ae_masks, ws);
    } else if (bid < OFF_FOCAL) {
        wh_part(bid - OFF_WH, wh_out, wh_target, wh_mask, ws, smem);
    } else if (bid < OFF_TAN) {
        focal_part(bid - OFF_FOCAL, cls_out, cls_mask, kp_out, kp_mask, ws, smem);
    } else if (bid < OFF_VAR) {
        tan_part(bid - OFF_TAN, tan_out, tan_normals, tan_points, ws, smem);
    } else {
        var_part(bid - OFF_VAR, ae_out, centers, kps, ws, smem);
    }
}

// ---- mega2: the lean bit-tested sweep ----
__global__ void __launch_bounds__(256)
k_mega2(const float* __restrict__ ae_out, const int* __restrict__ centers,
        float* __restrict__ ws) {
    __shared__ float smem[320];
    sweep_part(blockIdx.x, ae_out, centers, ws, smem);
}

// ---- finalize: 1 block ----
__global__ void __launch_bounds__(256)
k_final(const float* __restrict__ ws, float* __restrict__ out) {
    __shared__ float sbuf[4];
    int tid = threadIdx.x;
    float ae_v = 0.f;
    if (tid < 128) {   // tid = b*32 + n
        int b = tid >> 5, n = tid & 31;
        const float* base = ws + WS_INST + (size_t)b * 256 * 64 + n * 2;
        float sum = 0.f, cnt = 0.f;
        #pragma unroll 8
        for (int c = 0; c < 256; ++c) { sum += base[c * 64]; cnt += base[c * 64 + 1]; }
        // where(np>0, -(pos+neg)/max(np,1), -neg) == -sum/max(np,1)  (np==0 => pos==0)
        ae_v = -sum / fmaxf(cnt, 1.0f) + ws[WS_VAR + tid];
    }
    float ae_sum = block_reduce(ae_v, sbuf);

    float cls_sum = block_reduce(ws[WS_FOCAL + tid * 2], sbuf);
    float cls_cnt = block_reduce(ws[WS_FOCAL + tid * 2 + 1], sbuf);
    float kp_sum  = block_reduce(ws[WS_FOCAL + 512 + tid * 2], sbuf);
    float kp_cnt  = block_reduce(ws[WS_FOCAL + 512 + tid * 2 + 1], sbuf);
    float wh_sl   = block_reduce(ws[WS_WH + tid * 2], sbuf);
    float wh_ms   = block_reduce(ws[WS_WH + tid * 2 + 1], sbuf);
    float tan_sum = block_reduce(tid < 32 ? ws[WS_TAN + tid] : 0.f, sbuf);

    if (tid == 0) {
        float l_cls = -cls_sum / fmaxf(cls_cnt, 1.0f);
        float l_kp  = -kp_sum  / fmaxf(kp_cnt,  1.0f);
        float l_wh  = 0.1f * wh_sl / (wh_ms + 1e-4f);
        float l_ae  = ae_sum / (float)(NN * BB);
        float l_tan = tan_sum / (float)(PP * BB);
        out[0] = l_cls + l_wh + l_kp + l_ae + l_tan;
    }
}

extern "C" void kernel_launch(void* const* d_in, const int* in_sizes, int n_in,
                              void* d_out, int out_size, void* d_ws, size_t ws_size,
                              hipStream_t stream) {
    const float* cls_out     = (const float*)d_in[0];
    const float* wh_out      = (const float*)d_in[1];
    const float* kp_out      = (const float*)d_in[2];
    const float* ae_out      = (const float*)d_in[3];
    const float* tan_out     = (const float*)d_in[4];
    const float* cls_mask    = (const float*)d_in[5];
    const float* wh_target   = (const float*)d_in[6];
    const float* wh_mask     = (const float*)d_in[7];
    const float* kp_mask     = (const float*)d_in[8];
    const float* ae_masks    = (const float*)d_in[9];
    const float* tan_normals = (const float*)d_in[10];
    // d_in[11] = xym: analytic (y/512, x/512)
    const int* centers    = (const int*)d_in[12];
    const int* kps        = (const int*)d_in[13];
    const int* tan_points = (const int*)d_in[14];
    float* ws  = (float*)d_ws;
    float* out = (float*)d_out;

    k_mega1<<<NBLK_M1, 256, 0, stream>>>(cls_out, wh_out, kp_out, ae_out, tan_out,
                                         cls_mask, wh_target, wh_mask, kp_mask,
                                         ae_masks, tan_normals, centers, kps,
                                         tan_points, ws);
    k_mega2<<<NBLK_M2, 256, 0, stream>>>(ae_out, centers, ws);
    k_final<<<1, 256, 0, stream>>>(ws, out);
}

// Round 16
// 53.554 us; speedup vs baseline: 1.7001x; 1.7001x over previous
//
#include <hip/hip_runtime.h>
#include <math.h>

#define HW     262144   // 512*512
#define WIDTH  512
#define BB     4
#define NN     32
#define KK     256
#define PP     8192
#define EPSF   1e-4f
#define ONE_M_EPS (1.0f - 1e-4f)

// ---- block partition: inst first (longest), small families fill the tail ----
#define NBLK_INST  512   // (b:4) x (grp:4 of 8 inst) x (seg:32 of 32KB plane-segment)
#define NBLK_WH    256
#define NBLK_FOCAL 512   // 2 tensors x 256
#define NBLK_TAN   32
#define NBLK_VAR   128
#define OFF_WH     NBLK_INST
#define OFF_FOCAL  (OFF_WH + NBLK_WH)
#define OFF_TAN    (OFF_FOCAL + NBLK_FOCAL)
#define OFF_VAR    (OFF_TAN + NBLK_TAN)
#define NBLK_TOTAL (OFF_VAR + NBLK_VAR)   // 1440

// ---- workspace layout (floats) ----
#define WS_INST  0       // [512 blocks][16]  (il*2 + {sum,cnt}) = 8192
#define WS_FOCAL 8192    // [2][256][2] = 1024
#define WS_WH    9216    // [256][2]    = 512
#define WS_TAN   9728    // [32]
#define WS_VAR   9760    // [128]
// total 9888 floats

__device__ __forceinline__ float ftanh(float x) {
    float e = __expf(2.0f * x);
    return 1.0f - 2.0f / (e + 1.0f);
}

__device__ __forceinline__ float wave_reduce(float v) {
    #pragma unroll
    for (int off = 1; off < 64; off <<= 1) v += __shfl_xor(v, off, 64);
    return v;
}

__device__ __forceinline__ float block_reduce(float v, float* sbuf) {
    v = wave_reduce(v);
    int lane = threadIdx.x & 63, wid = threadIdx.x >> 6;
    __syncthreads();
    if (lane == 0) sbuf[wid] = v;
    __syncthreads();
    float r = 0.f;
    if (threadIdx.x == 0) {
        for (int i = 0; i < 4; ++i) r += sbuf[i];
    }
    return r;
}

// ---- AE instance focal: PLANE-SEQUENTIAL sweep (best measured: 53.6us bench) ----
// idx: b = idx>>7, grp = (idx>>5)&3 (8 instances), seg = idx&31 (32KB of plane).
// For each il: sweep the 32KB mask segment CONTIGUOUSLY (8 x 4KB block-steps),
// re-reading ae (L2/L3-resident). Only 2 live accumulators; reduce per il.
// No barriers in the hot loop. Every perturbation of this structure regressed
// (R11 precompute, R12 interchange, R13/R14 pairing, R15 bitplanes).
__device__ __forceinline__ void inst_part(int idx, const float* __restrict__ ae,
                                          const float* __restrict__ masks,
                                          const int* __restrict__ centers,
                                          float* __restrict__ ws,
                                          float* __restrict__ s_part) { // [4][16]
    const int tid = threadIdx.x, lane = tid & 63, w = tid >> 6;
    const int b = idx >> 7, grp = (idx >> 5) & 3, seg = idx & 31;
    const float4* aeb   = (const float4*)ae + (size_t)b * 4 * 65536;
    const float4* mbase = (const float4*)masks + ((size_t)(b * NN + grp * 8) << 16);
    const int segf4 = seg * 2048;     // 2048 f4 = 32KB
    const int* cb = centers + (b * NN + grp * 8) * 2;

    #pragma unroll 1
    for (int il = 0; il < 8; ++il) {
        float cy = (float)cb[il * 2]     * (1.0f / 512.0f);   // wave-uniform
        float cx = (float)cb[il * 2 + 1] * (1.0f / 512.0f);
        const float4* mp = mbase + ((size_t)il << 16) + segf4;
        float sum = 0.f, cnt = 0.f;
        float4 mk = mp[tid];
        #pragma unroll
        for (int it = 0; it < 8; ++it) {
            float4 mk_n;
            if (it < 7) mk_n = mp[(it + 1) * 256 + tid];     // sequential prefetch
            int v = segf4 + it * 256 + tid;
            float4 a0 = aeb[v];
            float4 a1 = aeb[65536 + v];
            float4 a2 = aeb[131072 + v];
            float4 a3 = aeb[196608 + v];
            int pix0 = v * 4;
            float fy  = (float)(pix0 >> 9)  * (1.0f / 512.0f);
            float fx0 = (float)(pix0 & 511) * (1.0f / 512.0f);
            #pragma unroll
            for (int j = 0; j < 4; ++j) {
                float se0 = ftanh((&a0.x)[j]) + fy;
                float se1 = ftanh((&a1.x)[j]) + fx0 + (float)j * (1.0f / 512.0f);
                float sg0 = __expf((&a2.x)[j]);
                float sg1 = __expf((&a3.x)[j]);
                float m  = (&mk.x)[j];                 // exactly 0.0 or 1.0
                float dy = se0 - cy, dx = se1 - cx;
                float s  = fmaf(dx * dx, sg1, dy * dy * sg0);
                float e  = __expf(-s);
                float pc = fminf(fmaxf(e, EPSF), ONE_M_EPS);
                float omp = 1.0f - pc;
                // pos: log(pc)*omp^2 ; neg: log(omp)*pc^2 (neg_w==1, binary mask)
                float A = (m != 0.f) ? pc : omp;
                float B = 1.0f - A;
                sum = fmaf(__logf(A), B * B, sum);
                cnt += m;
            }
            mk = mk_n;
        }
        float r0 = wave_reduce(sum);
        float r1 = wave_reduce(cnt);
        if (lane == 0) {
            s_part[w * 16 + il * 2 + 0] = r0;
            s_part[w * 16 + il * 2 + 1] = r1;
        }
    }
    __syncthreads();
    if (tid < 16) {
        float s = s_part[tid] + s_part[16 + tid] + s_part[32 + tid] + s_part[48 + tid];
        ws[WS_INST + idx * 16 + tid] = s;
    }
}

// ---- cls/kp focal: idx = t*256 + blk, 4 iters ----
__device__ __forceinline__ void focal_part(int idx, const float* __restrict__ cls_out,
                                           const float* __restrict__ cls_mask,
                                           const float* __restrict__ kp_out,
                                           const float* __restrict__ kp_mask,
                                           float* __restrict__ ws, float* sbuf) {
    int t = idx >> 8, blk = idx & 255;
    const float4* po = (const float4*)(t == 0 ? cls_out : kp_out);
    const float4* pm = (const float4*)(t == 0 ? cls_mask : kp_mask);
    float sum = 0.f, cnt = 0.f;
    #pragma unroll
    for (int it = 0; it < 4; ++it) {
        int i = blk * 256 + threadIdx.x + it * 65536;
        float4 xo = po[i], xm = pm[i];
        #pragma unroll
        for (int j = 0; j < 4; ++j) {
            float x = (&xo.x)[j], gt = (&xm.x)[j];
            float p = 1.0f / (1.0f + __expf(-x));
            p = fminf(fmaxf(p, EPSF), ONE_M_EPS);
            float omp = 1.0f - p;
            float pos_t = __logf(p) * omp * omp;
            float og = 1.0f - gt;
            float negw = og * og; negw *= negw;
            float neg_t = __logf(omp) * p * p * negw;
            bool ispos = (gt == 1.0f);
            sum += ispos ? pos_t : neg_t;
            cnt += ispos ? 1.0f : 0.0f;
        }
    }
    float r0 = block_reduce(sum, sbuf);
    float r1 = block_reduce(cnt, sbuf);
    if (threadIdx.x == 0) {
        ws[WS_FOCAL + idx * 2 + 0] = r0;
        ws[WS_FOCAL + idx * 2 + 1] = r1;
    }
}

__device__ __forceinline__ void wh_part(int blk, const float* __restrict__ o,
                                        const float* __restrict__ tg,
                                        const float* __restrict__ m,
                                        float* __restrict__ ws, float* sbuf) {
    const float4* po  = (const float4*)o;
    const float4* pt  = (const float4*)tg;
    const float4* pmk = (const float4*)m;
    float sl = 0.f, ms = 0.f;
    #pragma unroll
    for (int it = 0; it < 8; ++it) {
        int i = blk * 256 + threadIdx.x + it * 65536;
        float4 a = po[i], b = pt[i], c = pmk[i];
        #pragma unroll
        for (int j = 0; j < 4; ++j) {
            float mm = (&c.x)[j];
            float d  = (&a.x)[j] * mm - (&b.x)[j] * mm;
            float ad = fabsf(d);
            sl += (ad < 1.0f) ? 0.5f * d * d : (ad - 0.5f);
            ms += mm;
        }
    }
    float r0 = block_reduce(sl, sbuf);
    float r1 = block_reduce(ms, sbuf);
    if (threadIdx.x == 0) {
        ws[WS_WH + blk * 2 + 0] = r0;
        ws[WS_WH + blk * 2 + 1] = r1;
    }
}

__device__ __forceinline__ void tan_part(int idx, const float* __restrict__ tan_out,
                                         const float* __restrict__ normals,
                                         const int* __restrict__ pts,
                                         float* __restrict__ ws, float* sbuf) {
    int b = idx >> 3, seg = idx & 7;
    float s = 0.f;
    for (int p = seg * 1024 + threadIdx.x; p < seg * 1024 + 1024; p += 256) {
        int base = (b * PP + p) * 2;
        int py = pts[base], px = pts[base + 1];
        int pix = py * WIDTH + px;
        float t0 = tan_out[b * 2 * HW + pix];
        float t1 = tan_out[b * 2 * HW + HW + pix];
        float inv = 1.0f / fmaxf(sqrtf(t0 * t0 + t1 * t1), EPSF);
        float n0 = normals[base], n1 = normals[base + 1];
        s += 1.0f - (n0 * t0 + n1 * t1) * inv;
    }
    float r = block_reduce(s, sbuf);
    if (threadIdx.x == 0) ws[WS_TAN + idx] = r;
}

__device__ __forceinline__ void var_part(int idx, const float* __restrict__ ae,
                                         const int* __restrict__ centers,
                                         const int* __restrict__ kps,
                                         float* __restrict__ ws, float* smem) {
    int n = idx & 31, b = idx >> 5;
    float* cy = smem, *cx = smem + 32, *sbuf = smem + 64;
    if (threadIdx.x < NN) {
        int cb = (b * NN + threadIdx.x) * 2;
        cy[threadIdx.x] = centers[cb]     * (1.0f / 512.0f);
        cx[threadIdx.x] = centers[cb + 1] * (1.0f / 512.0f);
    }
    __syncthreads();
    int k = threadIdx.x;
    int kb = ((b * NN + n) * KK + k) * 2;
    int ky = kps[kb], kx = kps[kb + 1];
    int pix = ky * WIDTH + kx;
    const float* aeb = ae + (size_t)b * 4 * HW;
    float se0 = ftanh(aeb[pix])      + ky * (1.0f / 512.0f);
    float se1 = ftanh(aeb[HW + pix]) + kx * (1.0f / 512.0f);
    float sg0 = __expf(aeb[2 * HW + pix]);
    float sg1 = __expf(aeb[3 * HW + pix]);
    float own = 0.f, mx = -1e30f;
    #pragma unroll
    for (int m = 0; m < NN; ++m) {
        float d0 = se0 - cy[m], d1 = se1 - cx[m];
        float dist = __expf(-(d0 * d0 * sg0 + d1 * d1 * sg1));
        mx = fmaxf(mx, dist);
        if (m == n) own = dist;
    }
    float r = block_reduce(fabsf(own - mx), sbuf);
    if (threadIdx.x == 0) ws[WS_VAR + b * NN + n] = r;
}

// ---- the mega kernel: one dispatch for all partials ----
__global__ void __launch_bounds__(256)
k_mega(const float* __restrict__ cls_out, const float* __restrict__ wh_out,
       const float* __restrict__ kp_out,  const float* __restrict__ ae_out,
       const float* __restrict__ tan_out, const float* __restrict__ cls_mask,
       const float* __restrict__ wh_target, const float* __restrict__ wh_mask,
       const float* __restrict__ kp_mask, const float* __restrict__ ae_masks,
       const float* __restrict__ tan_normals,
       const int* __restrict__ centers, const int* __restrict__ kps,
       const int* __restrict__ tan_points, float* __restrict__ ws) {
    __shared__ float smem[256];
    int bid = blockIdx.x;
    if (bid < NBLK_INST) {
        inst_part(bid, ae_out, ae_masks, centers, ws, smem);
    } else if (bid < OFF_FOCAL) {
        wh_part(bid - OFF_WH, wh_out, wh_target, wh_mask, ws, smem);
    } else if (bid < OFF_TAN) {
        focal_part(bid - OFF_FOCAL, cls_out, cls_mask, kp_out, kp_mask, ws, smem);
    } else if (bid < OFF_VAR) {
        tan_part(bid - OFF_TAN, tan_out, tan_normals, tan_points, ws, smem);
    } else {
        var_part(bid - OFF_VAR, ae_out, centers, kps, ws, smem);
    }
}

// ---- finalize: 1 block ----
__global__ void __launch_bounds__(256)
k_final(const float* __restrict__ ws, float* __restrict__ out) {
    __shared__ float sbuf[4];
    int tid = threadIdx.x;
    float ae_v = 0.f;
    if (tid < 128) {   // tid = b*32 + n ; n = grp*8 + i
        int b = tid >> 5, n = tid & 31, grp = n >> 3, i = n & 7;
        const float* base = ws + WS_INST + ((b * 4 + grp) * 32) * 16 + i * 2;
        float sum = 0.f, cnt = 0.f;
        #pragma unroll 8
        for (int seg = 0; seg < 32; ++seg) { sum += base[seg * 16]; cnt += base[seg * 16 + 1]; }
        // where(np>0, -(pos+neg)/max(np,1), -neg) == -sum/max(np,1)  (np==0 => pos==0)
        ae_v = -sum / fmaxf(cnt, 1.0f) + ws[WS_VAR + tid];
    }
    float ae_sum = block_reduce(ae_v, sbuf);

    float cls_sum = block_reduce(ws[WS_FOCAL + tid * 2], sbuf);
    float cls_cnt = block_reduce(ws[WS_FOCAL + tid * 2 + 1], sbuf);
    float kp_sum  = block_reduce(ws[WS_FOCAL + 512 + tid * 2], sbuf);
    float kp_cnt  = block_reduce(ws[WS_FOCAL + 512 + tid * 2 + 1], sbuf);
    float wh_sl   = block_reduce(ws[WS_WH + tid * 2], sbuf);
    float wh_ms   = block_reduce(ws[WS_WH + tid * 2 + 1], sbuf);
    float tan_sum = block_reduce(tid < 32 ? ws[WS_TAN + tid] : 0.f, sbuf);

    if (tid == 0) {
        float l_cls = -cls_sum / fmaxf(cls_cnt, 1.0f);
        float l_kp  = -kp_sum  / fmaxf(kp_cnt,  1.0f);
        float l_wh  = 0.1f * wh_sl / (wh_ms + 1e-4f);
        float l_ae  = ae_sum / (float)(NN * BB);
        float l_tan = tan_sum / (float)(PP * BB);
        out[0] = l_cls + l_wh + l_kp + l_ae + l_tan;
    }
}

extern "C" void kernel_launch(void* const* d_in, const int* in_sizes, int n_in,
                              void* d_out, int out_size, void* d_ws, size_t ws_size,
                              hipStream_t stream) {
    const float* cls_out     = (const float*)d_in[0];
    const float* wh_out      = (const float*)d_in[1];
    const float* kp_out      = (const float*)d_in[2];
    const float* ae_out      = (const float*)d_in[3];
    const float* tan_out     = (const float*)d_in[4];
    const float* cls_mask    = (const float*)d_in[5];
    const float* wh_target   = (const float*)d_in[6];
    const float* wh_mask     = (const float*)d_in[7];
    const float* kp_mask     = (const float*)d_in[8];
    const float* ae_masks    = (const float*)d_in[9];
    const float* tan_normals = (const float*)d_in[10];
    // d_in[11] = xym: analytic (y/512, x/512)
    const int* centers    = (const int*)d_in[12];
    const int* kps        = (const int*)d_in[13];
    const int* tan_points = (const int*)d_in[14];
    float* ws  = (float*)d_ws;
    float* out = (float*)d_out;

    k_mega<<<NBLK_TOTAL, 256, 0, stream>>>(cls_out, wh_out, kp_out, ae_out, tan_out,
                                           cls_mask, wh_target, wh_mask, kp_mask,
                                           ae_masks, tan_normals, centers, kps,
                                           tan_points, ws);
    k_final<<<1, 256, 0, stream>>>(ws, out);
}